// Round 1
// baseline (7404.964 us; speedup 1.0000x reference)
//
#include <hip/hip_runtime.h>
#include <math.h>

#define T_SEQ   1000
#define BATCH   8
#define DMODEL  512
#define NHEAD   8
#define DHEAD   64
#define FFDIM   2048
#define NLAYER  4
#define MROWS   (BATCH * T_SEQ)   // 8000

// ---------------------------------------------------------------------------
// GEMM: C(MxN) = A(MxK) @ B(NxK)^T + bias, optional ReLU.  fp32.
// 128x128 block tile, BK=16, 256 threads, 8x8 micro-tile per thread.
// ---------------------------------------------------------------------------
template<bool RELU>
__global__ __launch_bounds__(256)
void gemm_nt(const float* __restrict__ A, const float* __restrict__ B,
             const float* __restrict__ bias, float* __restrict__ C,
             int M, int N, int K)
{
    __shared__ __align__(16) float As[16][132];
    __shared__ __align__(16) float Bs[16][132];

    const int tid  = threadIdx.x;
    const int tx   = tid & 15;       // 0..15  -> col group
    const int ty   = tid >> 4;       // 0..15  -> row group
    const int row0 = blockIdx.y * 128;
    const int col0 = blockIdx.x * 128;
    const int lr   = tid >> 2;       // 0..63 : row within tile for loading
    const int lk   = (tid & 3) << 2; // 0,4,8,12 : k offset

    float acc[8][8];
    #pragma unroll
    for (int i = 0; i < 8; ++i)
        #pragma unroll
        for (int j = 0; j < 8; ++j) acc[i][j] = 0.f;

    for (int kt = 0; kt < K; kt += 16) {
        #pragma unroll
        for (int p = 0; p < 2; ++p) {
            int r  = lr + p * 64;
            int gr = row0 + r;
            float4 v = make_float4(0.f, 0.f, 0.f, 0.f);
            if (gr < M) v = *(const float4*)(A + (size_t)gr * K + kt + lk);
            As[lk + 0][r] = v.x; As[lk + 1][r] = v.y;
            As[lk + 2][r] = v.z; As[lk + 3][r] = v.w;
            int gc = col0 + r;
            float4 w = make_float4(0.f, 0.f, 0.f, 0.f);
            if (gc < N) w = *(const float4*)(B + (size_t)gc * K + kt + lk);
            Bs[lk + 0][r] = w.x; Bs[lk + 1][r] = w.y;
            Bs[lk + 2][r] = w.z; Bs[lk + 3][r] = w.w;
        }
        __syncthreads();
        #pragma unroll
        for (int kk = 0; kk < 16; ++kk) {
            float a[8], b[8];
            *(float4*)&a[0] = *(const float4*)&As[kk][ty * 8];
            *(float4*)&a[4] = *(const float4*)&As[kk][ty * 8 + 4];
            *(float4*)&b[0] = *(const float4*)&Bs[kk][tx * 8];
            *(float4*)&b[4] = *(const float4*)&Bs[kk][tx * 8 + 4];
            #pragma unroll
            for (int i = 0; i < 8; ++i)
                #pragma unroll
                for (int j = 0; j < 8; ++j)
                    acc[i][j] = fmaf(a[i], b[j], acc[i][j]);
        }
        __syncthreads();
    }

    float bv[8];
    #pragma unroll
    for (int j = 0; j < 8; ++j) {
        int gc = col0 + tx * 8 + j;
        bv[j] = (gc < N) ? bias[gc] : 0.f;
    }
    #pragma unroll
    for (int i = 0; i < 8; ++i) {
        int gr = row0 + ty * 8 + i;
        if (gr >= M) continue;
        int gc0 = col0 + tx * 8;
        if (gc0 >= N) continue;
        float outv[8];
        #pragma unroll
        for (int j = 0; j < 8; ++j) {
            float v = acc[i][j] + bv[j];
            if (RELU) v = fmaxf(v, 0.f);
            outv[j] = v;
        }
        float* cp = C + (size_t)gr * N + gc0;
        *(float4*)cp       = *(float4*)&outv[0];
        *(float4*)(cp + 4) = *(float4*)&outv[4];
    }
}

// ---------------------------------------------------------------------------
// Add sinusoidal positional encoding in place. h is (BATCH, T_SEQ, DMODEL).
// ---------------------------------------------------------------------------
__global__ __launch_bounds__(256)
void add_pe(float* __restrict__ hbuf)
{
    int idx = blockIdx.x * 256 + threadIdx.x;       // over 8*1000*512
    int d   = idx & (DMODEL - 1);
    int t   = (idx >> 9) % T_SEQ;
    float freq = expf((float)(d & ~1) * (-9.210340371976184f / (float)DMODEL));
    float ang  = (float)t * freq;
    float pe   = (d & 1) ? cosf(ang) : sinf(ang);
    hbuf[idx] += pe;
}

// ---------------------------------------------------------------------------
// Banded attention. One wave (64 lanes) per (b, head, query-row); lane = dh.
// qkv is (BATCH*T, 3*DMODEL) with [q | k | v]; o is (BATCH*T, DMODEL).
// Online softmax over j in [i-w, i+w], w = 25*(head+1).
// ---------------------------------------------------------------------------
__global__ __launch_bounds__(256)
void band_attn(const float* __restrict__ qkv, float* __restrict__ o)
{
    const int wid  = threadIdx.x >> 6;
    const int lane = threadIdx.x & 63;
    const int r    = blockIdx.x * 4 + wid;          // 0 .. BATCH*NHEAD*T-1
    const int b    = r / (NHEAD * T_SEQ);
    const int rem  = r - b * NHEAD * T_SEQ;
    const int hh   = rem / T_SEQ;
    const int i    = rem - hh * T_SEQ;

    const float* kbase = qkv + (size_t)b * T_SEQ * (3 * DMODEL) + DMODEL + hh * DHEAD + lane;
    const float  q     = qkv[((size_t)b * T_SEQ + i) * (3 * DMODEL) + hh * DHEAD + lane];

    const int w  = 25 * (hh + 1);
    int j0 = i - w; if (j0 < 0) j0 = 0;
    int j1 = i + w; if (j1 > T_SEQ - 1) j1 = T_SEQ - 1;

    float m = -3.4e38f, l = 0.f, acc = 0.f;
    for (int j = j0; j <= j1; ++j) {
        float kv = kbase[(size_t)j * (3 * DMODEL)];
        float s  = q * kv;
        #pragma unroll
        for (int off = 32; off >= 1; off >>= 1) s += __shfl_xor(s, off, 64);
        s *= 0.125f;                         // 1/sqrt(64)
        float mn    = fmaxf(m, s);
        float scale = __expf(m - mn);
        float p     = __expf(s - mn);
        float vv    = kbase[(size_t)j * (3 * DMODEL) + DMODEL];
        l   = l * scale + p;
        acc = acc * scale + p * vv;
        m   = mn;
    }
    o[((size_t)b * T_SEQ + i) * DMODEL + hh * DHEAD + lane] = acc / l;
}

// ---------------------------------------------------------------------------
// h = LayerNorm(h + t) * g + b, row-wise over DMODEL. One wave per row.
// ---------------------------------------------------------------------------
__global__ __launch_bounds__(256)
void add_ln(float* __restrict__ hbuf, const float* __restrict__ tbuf,
            const float* __restrict__ g, const float* __restrict__ b)
{
    const int row  = blockIdx.x * 4 + (threadIdx.x >> 6);
    const int lane = threadIdx.x & 63;
    float*       hp = hbuf + (size_t)row * DMODEL + lane * 8;
    const float* tp = tbuf + (size_t)row * DMODEL + lane * 8;

    float xv[8];
    float4 h0 = *(const float4*)hp;       float4 h1 = *(const float4*)(hp + 4);
    float4 t0 = *(const float4*)tp;       float4 t1 = *(const float4*)(tp + 4);
    xv[0] = h0.x + t0.x; xv[1] = h0.y + t0.y; xv[2] = h0.z + t0.z; xv[3] = h0.w + t0.w;
    xv[4] = h1.x + t1.x; xv[5] = h1.y + t1.y; xv[6] = h1.z + t1.z; xv[7] = h1.w + t1.w;

    float s = 0.f;
    #pragma unroll
    for (int j = 0; j < 8; ++j) s += xv[j];
    #pragma unroll
    for (int off = 32; off >= 1; off >>= 1) s += __shfl_xor(s, off, 64);
    float mean = s * (1.f / DMODEL);

    float vs = 0.f;
    #pragma unroll
    for (int j = 0; j < 8; ++j) { float d = xv[j] - mean; vs += d * d; }
    #pragma unroll
    for (int off = 32; off >= 1; off >>= 1) vs += __shfl_xor(vs, off, 64);
    float rstd = rsqrtf(vs * (1.f / DMODEL) + 1e-5f);

    float4 g0 = *(const float4*)(g + lane * 8);
    float4 g1 = *(const float4*)(g + lane * 8 + 4);
    float4 b0 = *(const float4*)(b + lane * 8);
    float4 b1 = *(const float4*)(b + lane * 8 + 4);
    float gg[8] = {g0.x, g0.y, g0.z, g0.w, g1.x, g1.y, g1.z, g1.w};
    float bb[8] = {b0.x, b0.y, b0.z, b0.w, b1.x, b1.y, b1.z, b1.w};

    float outv[8];
    #pragma unroll
    for (int j = 0; j < 8; ++j)
        outv[j] = (xv[j] - mean) * rstd * gg[j] + bb[j];
    *(float4*)hp       = *(float4*)&outv[0];
    *(float4*)(hp + 4) = *(float4*)&outv[4];
}

// ---------------------------------------------------------------------------
// Max-pool over time + classifier + log_softmax. One block per batch item.
// ---------------------------------------------------------------------------
__global__ __launch_bounds__(256)
void pool_cls(const float* __restrict__ hbuf, const float* __restrict__ Wcls,
              const float* __restrict__ bcls, float* __restrict__ out)
{
    __shared__ float pooled[DMODEL];
    __shared__ float logits[8];
    const int bb  = blockIdx.x;
    const int tid = threadIdx.x;

    for (int d = tid; d < DMODEL; d += 256) {
        float mx = -3.4e38f;
        const float* p = hbuf + (size_t)bb * T_SEQ * DMODEL + d;
        for (int t = 0; t < T_SEQ; ++t) mx = fmaxf(mx, p[(size_t)t * DMODEL]);
        pooled[d] = mx;
    }
    __syncthreads();
    if (tid < 8) {
        float s = bcls[tid];
        const float* wr = Wcls + tid * DMODEL;
        for (int d = 0; d < DMODEL; ++d) s = fmaf(pooled[d], wr[d], s);
        logits[tid] = s;
    }
    __syncthreads();
    if (tid == 0) {
        float mx = logits[0];
        for (int c = 1; c < 8; ++c) mx = fmaxf(mx, logits[c]);
        float se = 0.f;
        for (int c = 0; c < 8; ++c) se += expf(logits[c] - mx);
        float lse = logf(se) + mx;
        for (int c = 0; c < 8; ++c) out[bb * 8 + c] = logits[c] - lse;
    }
}

// ---------------------------------------------------------------------------
extern "C" void kernel_launch(void* const* d_in, const int* in_sizes, int n_in,
                              void* d_out, int out_size, void* d_ws, size_t ws_size,
                              hipStream_t stream)
{
    const float* x    = (const float*)d_in[0];
    const float* Wemb = (const float*)d_in[1];
    const float* bemb = (const float*)d_in[2];
    const float* Wqkv = (const float*)d_in[3];
    const float* bqkv = (const float*)d_in[4];
    const float* Wo   = (const float*)d_in[5];
    const float* bo   = (const float*)d_in[6];
    const float* W1   = (const float*)d_in[7];
    const float* b1f  = (const float*)d_in[8];
    const float* W2   = (const float*)d_in[9];
    const float* b2f  = (const float*)d_in[10];
    const float* g1   = (const float*)d_in[11];
    const float* be1  = (const float*)d_in[12];
    const float* g2   = (const float*)d_in[13];
    const float* be2  = (const float*)d_in[14];
    const float* Wcls = (const float*)d_in[15];
    const float* bcls = (const float*)d_in[16];
    float* out = (float*)d_out;

    float* h   = (float*)d_ws;                       // 8000 x 512
    float* big = h   + (size_t)MROWS * DMODEL;       // 8000 x 2048 (qkv / ff1)
    float* tmp = big + (size_t)MROWS * FFDIM;        // 8000 x 512

    dim3 blk(256);

    // embedding + positional encoding
    gemm_nt<false><<<dim3(4, 63), blk, 0, stream>>>(x, Wemb, bemb, h, MROWS, DMODEL, 256);
    add_pe<<<dim3(MROWS * DMODEL / 256), blk, 0, stream>>>(h);

    for (int l = 0; l < NLAYER; ++l) {
        // qkv projection: (8000,512) @ (1536,512)^T
        gemm_nt<false><<<dim3(12, 63), blk, 0, stream>>>(
            h, Wqkv + (size_t)l * 3 * DMODEL * DMODEL, bqkv + (size_t)l * 3 * DMODEL,
            big, MROWS, 3 * DMODEL, DMODEL);
        // banded attention
        band_attn<<<dim3(MROWS * NHEAD / 4), blk, 0, stream>>>(big, tmp);
        // output projection
        gemm_nt<false><<<dim3(4, 63), blk, 0, stream>>>(
            tmp, Wo + (size_t)l * DMODEL * DMODEL, bo + (size_t)l * DMODEL,
            big, MROWS, DMODEL, DMODEL);
        // h = LN(h + attn_proj)
        add_ln<<<dim3(MROWS / 4), blk, 0, stream>>>(h, big, g1 + (size_t)l * DMODEL, be1 + (size_t)l * DMODEL);
        // FF1 + ReLU
        gemm_nt<true><<<dim3(16, 63), blk, 0, stream>>>(
            h, W1 + (size_t)l * FFDIM * DMODEL, b1f + (size_t)l * FFDIM,
            big, MROWS, FFDIM, DMODEL);
        // FF2
        gemm_nt<false><<<dim3(4, 63), blk, 0, stream>>>(
            big, W2 + (size_t)l * DMODEL * FFDIM, b2f + (size_t)l * DMODEL,
            tmp, MROWS, DMODEL, FFDIM);
        // h = LN(h + ff)
        add_ln<<<dim3(MROWS / 4), blk, 0, stream>>>(h, tmp, g2 + (size_t)l * DMODEL, be2 + (size_t)l * DMODEL);
    }

    pool_cls<<<dim3(8), blk, 0, stream>>>(h, Wcls, bcls, out);
}

// Round 2
// 4578.638 us; speedup vs baseline: 1.6173x; 1.6173x over previous
//
#include <hip/hip_runtime.h>
#include <math.h>

#define T_SEQ   1000
#define BATCH   8
#define DMODEL  512
#define NHEAD   8
#define DHEAD   64
#define FFDIM   2048
#define NLAYER  4
#define MROWS   (BATCH * T_SEQ)   // 8000

typedef __bf16 bf16x8 __attribute__((ext_vector_type(8)));
typedef __bf16 bf16x4 __attribute__((ext_vector_type(4)));
typedef float  f32x4  __attribute__((ext_vector_type(4)));

#define GL2LDS(g, l) \
    __builtin_amdgcn_global_load_lds((const __attribute__((address_space(1))) void*)(g), \
                                     (__attribute__((address_space(3))) void*)(l), 16, 0, 0)

// ---------------------------------------------------------------------------
// fp32 -> bf16 convert, 4 elems/thread. n must be divisible by 1024.
// ---------------------------------------------------------------------------
__global__ __launch_bounds__(256)
void f2bf(const float* __restrict__ in, __bf16* __restrict__ out)
{
    int i = (blockIdx.x * 256 + threadIdx.x) * 4;
    float4 v = *(const float4*)(in + i);
    bf16x4 o;
    o[0] = (__bf16)v.x; o[1] = (__bf16)v.y; o[2] = (__bf16)v.z; o[3] = (__bf16)v.w;
    *(bf16x4*)(out + i) = o;
}

// ---------------------------------------------------------------------------
// bf16 MFMA GEMM (m97 structure): C(MxN) = A(MxK) @ B(NxK)^T + bias.
// 128x128 tile, BK=64, 256 threads (4 waves, 2x2), 64x64 per wave,
// mfma_f32_16x16x32_bf16, global_load_lds width=16 staging.
// A rows clamped to M-1 for the M-tail; N,K must be multiples of 128/64.
// ---------------------------------------------------------------------------
template<bool WF32, bool WBF16, bool RELU>
__global__ __launch_bounds__(256)
void gemm_bf16(const __bf16* __restrict__ A, const __bf16* __restrict__ B,
               const float* __restrict__ bias, float* __restrict__ Cf,
               __bf16* __restrict__ Cb, int M, int N, int K)
{
    __shared__ __align__(16) __bf16 As[128 * 64];
    __shared__ __align__(16) __bf16 Bs[128 * 64];

    const int tid  = threadIdx.x;
    const int lane = tid & 63;
    const int w    = tid >> 6;
    const int wr   = w >> 1, wc = w & 1;
    const int row0 = blockIdx.y * 128;
    const int col0 = blockIdx.x * 128;

    // staging: 4 passes x 256 threads x 16B cover one 128x64 bf16 tile (16KB)
    size_t aoffg[4], boffg[4];
    int    ldso[4];
    #pragma unroll
    for (int p = 0; p < 4; ++p) {
        int bo = p * 4096 + tid * 16;
        int r  = bo >> 7;            // tile row (128B per row)
        int cb = bo & 127;           // byte within row
        int ga = row0 + r; if (ga > M - 1) ga = M - 1;   // clamp M tail
        aoffg[p] = (size_t)ga * K * 2 + cb;
        boffg[p] = (size_t)(col0 + r) * K * 2 + cb;
        ldso[p]  = bo;
    }

    f32x4 acc[4][4];
    #pragma unroll
    for (int m = 0; m < 4; ++m)
        #pragma unroll
        for (int n = 0; n < 4; ++n) acc[m][n] = (f32x4)0.f;

    const char* gA = (const char*)A;
    const char* gB = (const char*)B;
    char*       lA = (char*)As;
    char*       lB = (char*)Bs;

    for (int kt = 0; kt < K; kt += 64) {
        const size_t kb = (size_t)kt * 2;
        #pragma unroll
        for (int p = 0; p < 4; ++p) {
            GL2LDS(gA + aoffg[p] + kb, lA + ldso[p]);
            GL2LDS(gB + boffg[p] + kb, lB + ldso[p]);
        }
        __syncthreads();
        #pragma unroll
        for (int ks = 0; ks < 2; ++ks) {
            bf16x8 af[4], bfr[4];
            #pragma unroll
            for (int m = 0; m < 4; ++m) {
                int rr = wr * 64 + m * 16 + (lane & 15);
                af[m] = *(const bf16x8*)(As + rr * 64 + ks * 32 + (lane >> 4) * 8);
            }
            #pragma unroll
            for (int n = 0; n < 4; ++n) {
                int rr = wc * 64 + n * 16 + (lane & 15);
                bfr[n] = *(const bf16x8*)(Bs + rr * 64 + ks * 32 + (lane >> 4) * 8);
            }
            #pragma unroll
            for (int m = 0; m < 4; ++m)
                #pragma unroll
                for (int n = 0; n < 4; ++n)
                    acc[m][n] = __builtin_amdgcn_mfma_f32_16x16x32_bf16(af[m], bfr[n], acc[m][n], 0, 0, 0);
        }
        __syncthreads();
    }

    // epilogue: C/D layout col=lane&15, row=(lane>>4)*4+reg  [m89 verified]
    const int crow = (lane >> 4) * 4;
    const int ccol = lane & 15;
    #pragma unroll
    for (int n = 0; n < 4; ++n) {
        const int gc = col0 + wc * 64 + n * 16 + ccol;
        const float bv = bias[gc];
        #pragma unroll
        for (int m = 0; m < 4; ++m) {
            const int gr0 = row0 + wr * 64 + m * 16 + crow;
            #pragma unroll
            for (int r = 0; r < 4; ++r) {
                const int gr = gr0 + r;
                if (gr >= M) continue;
                float v = acc[m][n][r] + bv;
                if (RELU) v = fmaxf(v, 0.f);
                if (WF32)  Cf[(size_t)gr * N + gc] = v;
                if (WBF16) Cb[(size_t)gr * N + gc] = (__bf16)v;
            }
        }
    }
}

// ---------------------------------------------------------------------------
// Add sinusoidal PE in place (fp32) + write bf16 shadow.
// ---------------------------------------------------------------------------
__global__ __launch_bounds__(256)
void add_pe(float* __restrict__ hbuf, __bf16* __restrict__ hb)
{
    int idx = blockIdx.x * 256 + threadIdx.x;
    int d   = idx & (DMODEL - 1);
    int t   = (idx >> 9) % T_SEQ;
    float freq = expf((float)(d & ~1) * (-9.210340371976184f / (float)DMODEL));
    float ang  = (float)t * freq;
    float pe   = (d & 1) ? cosf(ang) : sinf(ang);
    float v = hbuf[idx] + pe;
    hbuf[idx] = v;
    hb[idx]   = (__bf16)v;
}

// ---------------------------------------------------------------------------
// Banded attention, bf16 in/out, fp32 math. One wave per (b,head,query row),
// lane = head dim. 8 keys per iteration for ILP on the shuffle-reduce chains.
// ---------------------------------------------------------------------------
__global__ __launch_bounds__(256)
void band_attn(const __bf16* __restrict__ qkv, __bf16* __restrict__ o)
{
    const int wid  = threadIdx.x >> 6;
    const int lane = threadIdx.x & 63;
    const int r    = blockIdx.x * 4 + wid;
    const int b    = r / (NHEAD * T_SEQ);
    const int rem  = r - b * (NHEAD * T_SEQ);
    const int hh   = rem / T_SEQ;
    const int i    = rem - hh * T_SEQ;

    const __bf16* base = qkv + (size_t)b * T_SEQ * (3 * DMODEL) + hh * DHEAD + lane;
    const float   q    = (float)base[(size_t)i * (3 * DMODEL)];
    const __bf16* kb   = base + DMODEL;
    const __bf16* vb   = base + 2 * DMODEL;

    const int w  = 25 * (hh + 1);
    int j0 = i - w; if (j0 < 0) j0 = 0;
    int j1 = i + w; if (j1 > T_SEQ - 1) j1 = T_SEQ - 1;

    float m = -3.4e38f, l = 0.f, acc = 0.f;
    for (int j = j0; j <= j1; j += 8) {
        float s[8];
        #pragma unroll
        for (int u = 0; u < 8; ++u) {
            int jj = j + u;
            float kv = (jj <= j1) ? (float)kb[(size_t)jj * (3 * DMODEL)] : 0.f;
            s[u] = q * kv;
        }
        #pragma unroll
        for (int off = 32; off >= 1; off >>= 1) {
            #pragma unroll
            for (int u = 0; u < 8; ++u) s[u] += __shfl_xor(s[u], off, 64);
        }
        float mx = m;
        #pragma unroll
        for (int u = 0; u < 8; ++u) {
            s[u] = (j + u <= j1) ? s[u] * 0.125f : -3.4e38f;
            mx = fmaxf(mx, s[u]);
        }
        const float scale = __expf(m - mx);
        float p[8], ps = 0.f, pv = 0.f;
        #pragma unroll
        for (int u = 0; u < 8; ++u) {
            p[u] = __expf(s[u] - mx);          // OOB lanes -> exp(-inf) = 0
            ps += p[u];
        }
        #pragma unroll
        for (int u = 0; u < 8; ++u) {
            int jj = (j + u <= j1) ? j + u : j1;
            float vv = (float)vb[(size_t)jj * (3 * DMODEL)];
            pv = fmaf(p[u], vv, pv);
        }
        l   = fmaf(l, scale, ps);
        acc = fmaf(acc, scale, pv);
        m   = mx;
    }
    o[((size_t)b * T_SEQ + i) * DMODEL + hh * DHEAD + lane] = (__bf16)(acc / l);
}

// ---------------------------------------------------------------------------
// h = LayerNorm(h + t) * g + b (fp32 residual stream) + bf16 shadow.
// ---------------------------------------------------------------------------
__global__ __launch_bounds__(256)
void add_ln(float* __restrict__ hbuf, const float* __restrict__ tbuf,
            const float* __restrict__ g, const float* __restrict__ b,
            __bf16* __restrict__ hb)
{
    const int row  = blockIdx.x * 4 + (threadIdx.x >> 6);
    const int lane = threadIdx.x & 63;
    float*       hp = hbuf + (size_t)row * DMODEL + lane * 8;
    const float* tp = tbuf + (size_t)row * DMODEL + lane * 8;

    float xv[8];
    float4 h0 = *(const float4*)hp;   float4 h1 = *(const float4*)(hp + 4);
    float4 t0 = *(const float4*)tp;   float4 t1 = *(const float4*)(tp + 4);
    xv[0] = h0.x + t0.x; xv[1] = h0.y + t0.y; xv[2] = h0.z + t0.z; xv[3] = h0.w + t0.w;
    xv[4] = h1.x + t1.x; xv[5] = h1.y + t1.y; xv[6] = h1.z + t1.z; xv[7] = h1.w + t1.w;

    float s = 0.f;
    #pragma unroll
    for (int j = 0; j < 8; ++j) s += xv[j];
    #pragma unroll
    for (int off = 32; off >= 1; off >>= 1) s += __shfl_xor(s, off, 64);
    float mean = s * (1.f / DMODEL);

    float vs = 0.f;
    #pragma unroll
    for (int j = 0; j < 8; ++j) { float d = xv[j] - mean; vs += d * d; }
    #pragma unroll
    for (int off = 32; off >= 1; off >>= 1) vs += __shfl_xor(vs, off, 64);
    float rstd = rsqrtf(vs * (1.f / DMODEL) + 1e-5f);

    float4 g0 = *(const float4*)(g + lane * 8);
    float4 g1 = *(const float4*)(g + lane * 8 + 4);
    float4 b0 = *(const float4*)(b + lane * 8);
    float4 b1 = *(const float4*)(b + lane * 8 + 4);
    float gg[8] = {g0.x, g0.y, g0.z, g0.w, g1.x, g1.y, g1.z, g1.w};
    float bb[8] = {b0.x, b0.y, b0.z, b0.w, b1.x, b1.y, b1.z, b1.w};

    float outv[8];
    bf16x8 ob;
    #pragma unroll
    for (int j = 0; j < 8; ++j) {
        outv[j] = (xv[j] - mean) * rstd * gg[j] + bb[j];
        ob[j] = (__bf16)outv[j];
    }
    *(float4*)hp       = *(float4*)&outv[0];
    *(float4*)(hp + 4) = *(float4*)&outv[4];
    *(bf16x8*)(hb + (size_t)row * DMODEL + lane * 8) = ob;
}

// ---------------------------------------------------------------------------
// Max-pool over time + classifier + log_softmax. One block per batch item.
// ---------------------------------------------------------------------------
__global__ __launch_bounds__(256)
void pool_cls(const float* __restrict__ hbuf, const float* __restrict__ Wcls,
              const float* __restrict__ bcls, float* __restrict__ out)
{
    __shared__ float pooled[DMODEL];
    __shared__ float logits[8];
    const int bb  = blockIdx.x;
    const int tid = threadIdx.x;

    for (int d = tid; d < DMODEL; d += 256) {
        float mx = -3.4e38f;
        const float* p = hbuf + (size_t)bb * T_SEQ * DMODEL + d;
        for (int t = 0; t < T_SEQ; ++t) mx = fmaxf(mx, p[(size_t)t * DMODEL]);
        pooled[d] = mx;
    }
    __syncthreads();
    if (tid < 8) {
        float s = bcls[tid];
        const float* wr = Wcls + tid * DMODEL;
        for (int d = 0; d < DMODEL; ++d) s = fmaf(pooled[d], wr[d], s);
        logits[tid] = s;
    }
    __syncthreads();
    if (tid == 0) {
        float mx = logits[0];
        for (int c = 1; c < 8; ++c) mx = fmaxf(mx, logits[c]);
        float se = 0.f;
        for (int c = 0; c < 8; ++c) se += expf(logits[c] - mx);
        float lse = logf(se) + mx;
        for (int c = 0; c < 8; ++c) out[bb * 8 + c] = logits[c] - lse;
    }
}

// ---------------------------------------------------------------------------
extern "C" void kernel_launch(void* const* d_in, const int* in_sizes, int n_in,
                              void* d_out, int out_size, void* d_ws, size_t ws_size,
                              hipStream_t stream)
{
    const float* x    = (const float*)d_in[0];
    const float* Wemb = (const float*)d_in[1];
    const float* bemb = (const float*)d_in[2];
    const float* Wqkv = (const float*)d_in[3];
    const float* bqkv = (const float*)d_in[4];
    const float* Wo   = (const float*)d_in[5];
    const float* bo   = (const float*)d_in[6];
    const float* W1   = (const float*)d_in[7];
    const float* b1f  = (const float*)d_in[8];
    const float* W2   = (const float*)d_in[9];
    const float* b2f  = (const float*)d_in[10];
    const float* g1   = (const float*)d_in[11];
    const float* be1  = (const float*)d_in[12];
    const float* g2   = (const float*)d_in[13];
    const float* be2  = (const float*)d_in[14];
    const float* Wcls = (const float*)d_in[15];
    const float* bcls = (const float*)d_in[16];
    float* out = (float*)d_out;

    // -------- workspace layout --------
    float*  h    = (float*)d_ws;                       // 8000x512 f32
    float*  tmpF = h + (size_t)MROWS * DMODEL;         // 8000x512 f32
    __bf16* hb   = (__bf16*)(tmpF + (size_t)MROWS * DMODEL);   // 8000x512
    __bf16* qkvb = hb + (size_t)MROWS * DMODEL;        // 8000x1536
    __bf16* attb = qkvb + (size_t)MROWS * 3 * DMODEL;  // 8000x512
    __bf16* ff1b = qkvb;                               // alias: 8000x2048 over qkvb+attb
    __bf16* xb   = attb + (size_t)MROWS * DMODEL;      // 8000x256
    __bf16* wb   = xb + (size_t)MROWS * 256;           // bf16 weights
    __bf16* wEmb = wb;                                 // 512*256
    __bf16* wQKV = wEmb + 512 * 256;                   // 4*1536*512
    __bf16* wWo  = wQKV + (size_t)NLAYER * 3 * DMODEL * DMODEL;
    __bf16* wW1  = wWo  + (size_t)NLAYER * DMODEL * DMODEL;
    __bf16* wW2  = wW1  + (size_t)NLAYER * FFDIM * DMODEL;

    dim3 blk(256);

    // -------- weight / input conversion to bf16 --------
    f2bf<<<dim3(MROWS * 256 / 1024), blk, 0, stream>>>(x, xb);
    f2bf<<<dim3(512 * 256 / 1024), blk, 0, stream>>>(Wemb, wEmb);
    f2bf<<<dim3(NLAYER * 3 * DMODEL * DMODEL / 1024), blk, 0, stream>>>(Wqkv, wQKV);
    f2bf<<<dim3(NLAYER * DMODEL * DMODEL / 1024), blk, 0, stream>>>(Wo, wWo);
    f2bf<<<dim3(NLAYER * FFDIM * DMODEL / 1024), blk, 0, stream>>>(W1, wW1);
    f2bf<<<dim3(NLAYER * DMODEL * FFDIM / 1024), blk, 0, stream>>>(W2, wW2);

    // -------- embedding + PE --------
    gemm_bf16<true, false, false><<<dim3(4, 63), blk, 0, stream>>>(
        xb, wEmb, bemb, h, nullptr, MROWS, DMODEL, 256);
    add_pe<<<dim3(MROWS * DMODEL / 256), blk, 0, stream>>>(h, hb);

    for (int l = 0; l < NLAYER; ++l) {
        gemm_bf16<false, true, false><<<dim3(12, 63), blk, 0, stream>>>(
            hb, wQKV + (size_t)l * 3 * DMODEL * DMODEL, bqkv + (size_t)l * 3 * DMODEL,
            nullptr, qkvb, MROWS, 3 * DMODEL, DMODEL);
        band_attn<<<dim3(MROWS * NHEAD / 4), blk, 0, stream>>>(qkvb, attb);
        gemm_bf16<true, false, false><<<dim3(4, 63), blk, 0, stream>>>(
            attb, wWo + (size_t)l * DMODEL * DMODEL, bo + (size_t)l * DMODEL,
            tmpF, nullptr, MROWS, DMODEL, DMODEL);
        add_ln<<<dim3(MROWS / 4), blk, 0, stream>>>(
            h, tmpF, g1 + (size_t)l * DMODEL, be1 + (size_t)l * DMODEL, hb);
        gemm_bf16<false, true, true><<<dim3(16, 63), blk, 0, stream>>>(
            hb, wW1 + (size_t)l * FFDIM * DMODEL, b1f + (size_t)l * FFDIM,
            nullptr, ff1b, MROWS, FFDIM, DMODEL);
        gemm_bf16<true, false, false><<<dim3(4, 63), blk, 0, stream>>>(
            ff1b, wW2 + (size_t)l * DMODEL * FFDIM, b2f + (size_t)l * DMODEL,
            tmpF, nullptr, MROWS, DMODEL, FFDIM);
        add_ln<<<dim3(MROWS / 4), blk, 0, stream>>>(
            h, tmpF, g2 + (size_t)l * DMODEL, be2 + (size_t)l * DMODEL, hb);
    }

    pool_cls<<<dim3(8), blk, 0, stream>>>(h, Wcls, bcls, out);
}

// Round 3
// 1210.295 us; speedup vs baseline: 6.1183x; 3.7831x over previous
//
#include <hip/hip_runtime.h>
#include <math.h>

#define T_SEQ   1000
#define BATCH   8
#define DMODEL  512
#define NHEAD   8
#define DHEAD   64
#define FFDIM   2048
#define NLAYER  4
#define MROWS   (BATCH * T_SEQ)   // 8000

typedef __bf16 bf16x8 __attribute__((ext_vector_type(8)));
typedef __bf16 bf16x4 __attribute__((ext_vector_type(4)));
typedef float  f32x4  __attribute__((ext_vector_type(4)));
typedef float  f32x16 __attribute__((ext_vector_type(16)));

#define GL2LDS(g, l) \
    __builtin_amdgcn_global_load_lds((const __attribute__((address_space(1))) void*)(g), \
                                     (__attribute__((address_space(3))) void*)(l), 16, 0, 0)

// ---------------------------------------------------------------------------
// fp32 -> bf16 convert, 4 elems/thread.
// ---------------------------------------------------------------------------
__global__ __launch_bounds__(256)
void f2bf(const float* __restrict__ in, __bf16* __restrict__ out)
{
    int i = (blockIdx.x * 256 + threadIdx.x) * 4;
    float4 v = *(const float4*)(in + i);
    bf16x4 o;
    o[0] = (__bf16)v.x; o[1] = (__bf16)v.y; o[2] = (__bf16)v.z; o[3] = (__bf16)v.w;
    *(bf16x4*)(out + i) = o;
}

// ---------------------------------------------------------------------------
// bf16 MFMA GEMM (m97 structure): C(MxN) = A(MxK) @ B(NxK)^T + bias.
// ---------------------------------------------------------------------------
template<bool WF32, bool WBF16, bool RELU>
__global__ __launch_bounds__(256)
void gemm_bf16(const __bf16* __restrict__ A, const __bf16* __restrict__ B,
               const float* __restrict__ bias, float* __restrict__ Cf,
               __bf16* __restrict__ Cb, int M, int N, int K)
{
    __shared__ __align__(16) __bf16 As[128 * 64];
    __shared__ __align__(16) __bf16 Bs[128 * 64];

    const int tid  = threadIdx.x;
    const int lane = tid & 63;
    const int w    = tid >> 6;
    const int wr   = w >> 1, wc = w & 1;
    const int row0 = blockIdx.y * 128;
    const int col0 = blockIdx.x * 128;

    size_t aoffg[4], boffg[4];
    int    ldso[4];
    #pragma unroll
    for (int p = 0; p < 4; ++p) {
        int bo = p * 4096 + tid * 16;
        int r  = bo >> 7;
        int cb = bo & 127;
        int ga = row0 + r; if (ga > M - 1) ga = M - 1;
        aoffg[p] = (size_t)ga * K * 2 + cb;
        boffg[p] = (size_t)(col0 + r) * K * 2 + cb;
        ldso[p]  = bo;
    }

    f32x4 acc[4][4];
    #pragma unroll
    for (int m = 0; m < 4; ++m)
        #pragma unroll
        for (int n = 0; n < 4; ++n) acc[m][n] = (f32x4)0.f;

    const char* gA = (const char*)A;
    const char* gB = (const char*)B;
    char*       lA = (char*)As;
    char*       lB = (char*)Bs;

    for (int kt = 0; kt < K; kt += 64) {
        const size_t kb = (size_t)kt * 2;
        #pragma unroll
        for (int p = 0; p < 4; ++p) {
            GL2LDS(gA + aoffg[p] + kb, lA + ldso[p]);
            GL2LDS(gB + boffg[p] + kb, lB + ldso[p]);
        }
        __syncthreads();
        #pragma unroll
        for (int ks = 0; ks < 2; ++ks) {
            bf16x8 af[4], bfr[4];
            #pragma unroll
            for (int m = 0; m < 4; ++m) {
                int rr = wr * 64 + m * 16 + (lane & 15);
                af[m] = *(const bf16x8*)(As + rr * 64 + ks * 32 + (lane >> 4) * 8);
            }
            #pragma unroll
            for (int n = 0; n < 4; ++n) {
                int rr = wc * 64 + n * 16 + (lane & 15);
                bfr[n] = *(const bf16x8*)(Bs + rr * 64 + ks * 32 + (lane >> 4) * 8);
            }
            #pragma unroll
            for (int m = 0; m < 4; ++m)
                #pragma unroll
                for (int n = 0; n < 4; ++n)
                    acc[m][n] = __builtin_amdgcn_mfma_f32_16x16x32_bf16(af[m], bfr[n], acc[m][n], 0, 0, 0);
        }
        __syncthreads();
    }

    const int crow = (lane >> 4) * 4;
    const int ccol = lane & 15;
    #pragma unroll
    for (int n = 0; n < 4; ++n) {
        const int gc = col0 + wc * 64 + n * 16 + ccol;
        const float bv = bias[gc];
        #pragma unroll
        for (int m = 0; m < 4; ++m) {
            const int gr0 = row0 + wr * 64 + m * 16 + crow;
            #pragma unroll
            for (int r = 0; r < 4; ++r) {
                const int gr = gr0 + r;
                if (gr >= M) continue;
                float v = acc[m][n][r] + bv;
                if (RELU) v = fmaxf(v, 0.f);
                if (WF32)  Cf[(size_t)gr * N + gc] = v;
                if (WBF16) Cb[(size_t)gr * N + gc] = (__bf16)v;
            }
        }
    }
}

// ---------------------------------------------------------------------------
// Add sinusoidal PE in place (fp32) + write bf16 shadow.
// ---------------------------------------------------------------------------
__global__ __launch_bounds__(256)
void add_pe(float* __restrict__ hbuf, __bf16* __restrict__ hb)
{
    int idx = blockIdx.x * 256 + threadIdx.x;
    int d   = idx & (DMODEL - 1);
    int t   = (idx >> 9) % T_SEQ;
    float freq = expf((float)(d & ~1) * (-9.210340371976184f / (float)DMODEL));
    float ang  = (float)t * freq;
    float pe   = (d & 1) ? cosf(ang) : sinf(ang);
    float v = hbuf[idx] + pe;
    hbuf[idx] = v;
    hb[idx]   = (__bf16)v;
}

// ---------------------------------------------------------------------------
// MFMA flash attention over the band, 32x32x16, swapped-operand structure.
// One wave per (b, h, 32-row q-tile). No LDS: K/V read from L2.
//
// S^T = mfma(A=K, B=Q): lane holds S[q = lane&31][key = (r&3)+8(r>>2)+4*(lane>>5)]
// (C/D layout: col=lane&31, row=(reg&3)+8*(reg>>2)+4*(lane>>5), m74/m101.)
// A/B-frag layout: row/col = lane&31, k = (lane>>5)*8 + j.
// ---------------------------------------------------------------------------
__global__ __launch_bounds__(256)
void attn_mfma(const __bf16* __restrict__ qkv, __bf16* __restrict__ o)
{
    const int wv   = (blockIdx.x << 2) + (threadIdx.x >> 6);
    const int lane = threadIdx.x & 63;
    const int qt   = wv & 31;
    const int hh   = (wv >> 5) & 7;
    const int b    = wv >> 8;
    const int qb   = qt * 32;
    const int half = lane >> 5;
    const int ql   = lane & 31;
    const int i    = qb + ql;                 // query row (may exceed 999)
    const int iq   = (i < T_SEQ) ? i : (T_SEQ - 1);

    const int RS = 3 * DMODEL;                // qkv row stride (elements)
    const __bf16* Q = qkv + (size_t)b * T_SEQ * RS + hh * DHEAD;
    const __bf16* K = Q + DMODEL;
    const __bf16* V = Q + 2 * DMODEL;

    // Q B-fragments, hoisted: qf[ds][j] = Q[i][ds*16 + half*8 + j]
    bf16x8 qf[4];
    {
        const __bf16* qrow = Q + (size_t)iq * RS + half * 8;
        #pragma unroll
        for (int ds = 0; ds < 4; ++ds)
            qf[ds] = *(const bf16x8*)(qrow + ds * 16);
    }

    const int w = 25 * (hh + 1);
    const int kb_lo = (qb - w > 0 ? qb - w : 0) & ~31;
    const int kb_hi = (qb + 31 + w < T_SEQ - 1) ? (qb + 31 + w) : (T_SEQ - 1);
    // valid iff 0 <= (j - (i-w)) <= span,  span = min(2w, 999-i+w)
    const int  spanv = (2 * w < T_SEQ - 1 - i + w) ? 2 * w : (T_SEQ - 1 - i + w);
    const unsigned span = (unsigned)spanv;
    const float C2 = 0.125f * 1.44269504089f; // (1/sqrt(dh)) * log2(e)

    float m2 = -1e9f, l = 0.f;
    f32x16 oa0 = (f32x16)0.f, oa1 = (f32x16)0.f;

    for (int kb = kb_lo; kb <= kb_hi; kb += 32) {
        // ---- QK^T (swapped): A = K-tile rows kb..kb+31 ----
        f32x16 sv = (f32x16)0.f;
        {
            int krow = kb + ql; if (krow > T_SEQ - 1) krow = T_SEQ - 1;
            const __bf16* kr = K + (size_t)krow * RS + half * 8;
            #pragma unroll
            for (int ds = 0; ds < 4; ++ds) {
                bf16x8 kf = *(const bf16x8*)(kr + ds * 16);
                sv = __builtin_amdgcn_mfma_f32_32x32x16_bf16(kf, qf[ds], sv, 0, 0, 0);
            }
        }

        // ---- mask + scale to base-2 domain ----
        const int base = kb - i + w;
        float s2[16];
        #pragma unroll
        for (int r = 0; r < 16; ++r) {
            const int kr = (r & 3) + 8 * (r >> 2) + 4 * half;
            const unsigned jrel = (unsigned)(base + kr);
            s2[r] = (jrel <= span) ? sv[r] * C2 : -1e9f;
        }

        // ---- block max (per q: in-lane 16 + xor32) ----
        float mx = s2[0];
        #pragma unroll
        for (int r = 1; r < 16; ++r) mx = fmaxf(mx, s2[r]);
        mx = fmaxf(mx, __shfl_xor(mx, 32, 64));

        // ---- defer-max rescale (T13, THR=8) ----
        if (!__all(mx <= m2 + 8.0f)) {
            const float mnew  = fmaxf(m2, mx);
            const float scale = exp2f(m2 - mnew);
            m2 = mnew;
            l *= scale;
            #pragma unroll
            for (int r = 0; r < 16; ++r) {
                const int qsrc = (r & 3) + 8 * (r >> 2) + 4 * half;
                const float sc = __shfl(scale, qsrc, 64);
                oa0[r] *= sc;
                oa1[r] *= sc;
            }
        }

        // ---- p = exp2(s2 - m2), row-sum ----
        float p[16];
        float ps = 0.f;
        #pragma unroll
        for (int r = 0; r < 16; ++r) { p[r] = exp2f(s2[r] - m2); ps += p[r]; }
        ps += __shfl_xor(ps, 32, 64);
        l += ps;

        // ---- build P A-fragments (bf16) for the two 16-key PV steps ----
        unsigned pk[8];
        #pragma unroll
        for (int t = 0; t < 8; ++t) {
            union { unsigned u; __bf16 h[2]; } cv;
            cv.h[0] = (__bf16)p[2 * t];
            cv.h[1] = (__bf16)p[2 * t + 1];
            pk[t] = cv.u;
        }
        unsigned y[8];
        #pragma unroll
        for (int t = 0; t < 8; ++t)
            y[t] = (unsigned)__shfl_xor((int)pk[t], 32, 64);

        union { unsigned u[4]; bf16x8 v; } pa0, pa1;
        if (half == 0) {
            pa0.u[0] = pk[0]; pa0.u[1] = pk[1]; pa0.u[2] = y[0];  pa0.u[3] = y[1];
            pa1.u[0] = pk[4]; pa1.u[1] = pk[5]; pa1.u[2] = y[4];  pa1.u[3] = y[5];
        } else {
            pa0.u[0] = y[2];  pa0.u[1] = y[3];  pa0.u[2] = pk[2]; pa0.u[3] = pk[3];
            pa1.u[0] = y[6];  pa1.u[1] = y[7];  pa1.u[2] = pk[6]; pa1.u[3] = pk[7];
        }

        // ---- PV: O[q][d] += P * V, two key-steps x two d-halves ----
        #pragma unroll
        for (int ks = 0; ks < 2; ++ks) {
            const int R0 = kb + ks * 16 + half * 8;
            #pragma unroll
            for (int dh = 0; dh < 2; ++dh) {
                bf16x8 vf;
                const __bf16* vcol = V + dh * 32 + ql;
                #pragma unroll
                for (int j = 0; j < 8; ++j) {
                    int rr = R0 + j; if (rr > T_SEQ - 1) rr = T_SEQ - 1;
                    vf[j] = vcol[(size_t)rr * RS];
                }
                if (dh == 0)
                    oa0 = __builtin_amdgcn_mfma_f32_32x32x16_bf16(ks ? pa1.v : pa0.v, vf, oa0, 0, 0, 0);
                else
                    oa1 = __builtin_amdgcn_mfma_f32_32x32x16_bf16(ks ? pa1.v : pa0.v, vf, oa1, 0, 0, 0);
            }
        }
    }

    // ---- epilogue: O / l, store bf16 ----
    const float rinv = 1.f / l;
    __bf16* ob = o + ((size_t)b * T_SEQ) * DMODEL + hh * DHEAD;
    #pragma unroll
    for (int r = 0; r < 16; ++r) {
        const int q   = (r & 3) + 8 * (r >> 2) + 4 * half;
        const int row = qb + q;
        const float ri = __shfl(rinv, q, 64);
        if (row < T_SEQ) {
            ob[(size_t)row * DMODEL + ql]      = (__bf16)(oa0[r] * ri);
            ob[(size_t)row * DMODEL + 32 + ql] = (__bf16)(oa1[r] * ri);
        }
    }
}

// ---------------------------------------------------------------------------
// h = LayerNorm(h + t) * g + b (fp32 residual stream) + bf16 shadow.
// ---------------------------------------------------------------------------
__global__ __launch_bounds__(256)
void add_ln(float* __restrict__ hbuf, const float* __restrict__ tbuf,
            const float* __restrict__ g, const float* __restrict__ b,
            __bf16* __restrict__ hb)
{
    const int row  = blockIdx.x * 4 + (threadIdx.x >> 6);
    const int lane = threadIdx.x & 63;
    float*       hp = hbuf + (size_t)row * DMODEL + lane * 8;
    const float* tp = tbuf + (size_t)row * DMODEL + lane * 8;

    float xv[8];
    float4 h0 = *(const float4*)hp;   float4 h1 = *(const float4*)(hp + 4);
    float4 t0 = *(const float4*)tp;   float4 t1 = *(const float4*)(tp + 4);
    xv[0] = h0.x + t0.x; xv[1] = h0.y + t0.y; xv[2] = h0.z + t0.z; xv[3] = h0.w + t0.w;
    xv[4] = h1.x + t1.x; xv[5] = h1.y + t1.y; xv[6] = h1.z + t1.z; xv[7] = h1.w + t1.w;

    float s = 0.f;
    #pragma unroll
    for (int j = 0; j < 8; ++j) s += xv[j];
    #pragma unroll
    for (int off = 32; off >= 1; off >>= 1) s += __shfl_xor(s, off, 64);
    float mean = s * (1.f / DMODEL);

    float vs = 0.f;
    #pragma unroll
    for (int j = 0; j < 8; ++j) { float d = xv[j] - mean; vs += d * d; }
    #pragma unroll
    for (int off = 32; off >= 1; off >>= 1) vs += __shfl_xor(vs, off, 64);
    float rstd = rsqrtf(vs * (1.f / DMODEL) + 1e-5f);

    float4 g0 = *(const float4*)(g + lane * 8);
    float4 g1 = *(const float4*)(g + lane * 8 + 4);
    float4 b0 = *(const float4*)(b + lane * 8);
    float4 b1 = *(const float4*)(b + lane * 8 + 4);
    float gg[8] = {g0.x, g0.y, g0.z, g0.w, g1.x, g1.y, g1.z, g1.w};
    float bb[8] = {b0.x, b0.y, b0.z, b0.w, b1.x, b1.y, b1.z, b1.w};

    float outv[8];
    bf16x8 ob;
    #pragma unroll
    for (int j = 0; j < 8; ++j) {
        outv[j] = (xv[j] - mean) * rstd * gg[j] + bb[j];
        ob[j] = (__bf16)outv[j];
    }
    *(float4*)hp       = *(float4*)&outv[0];
    *(float4*)(hp + 4) = *(float4*)&outv[4];
    *(bf16x8*)(hb + (size_t)row * DMODEL + lane * 8) = ob;
}

// ---------------------------------------------------------------------------
// Max-pool over time + classifier + log_softmax. One block per batch item.
// ---------------------------------------------------------------------------
__global__ __launch_bounds__(256)
void pool_cls(const float* __restrict__ hbuf, const float* __restrict__ Wcls,
              const float* __restrict__ bcls, float* __restrict__ out)
{
    __shared__ float pooled[DMODEL];
    __shared__ float logits[8];
    const int bb  = blockIdx.x;
    const int tid = threadIdx.x;

    for (int d = tid; d < DMODEL; d += 256) {
        float mx = -3.4e38f;
        const float* p = hbuf + (size_t)bb * T_SEQ * DMODEL + d;
        for (int t = 0; t < T_SEQ; ++t) mx = fmaxf(mx, p[(size_t)t * DMODEL]);
        pooled[d] = mx;
    }
    __syncthreads();
    if (tid < 8) {
        float s = bcls[tid];
        const float* wr = Wcls + tid * DMODEL;
        for (int d = 0; d < DMODEL; ++d) s = fmaf(pooled[d], wr[d], s);
        logits[tid] = s;
    }
    __syncthreads();
    if (tid == 0) {
        float mx = logits[0];
        for (int c = 1; c < 8; ++c) mx = fmaxf(mx, logits[c]);
        float se = 0.f;
        for (int c = 0; c < 8; ++c) se += expf(logits[c] - mx);
        float lse = logf(se) + mx;
        for (int c = 0; c < 8; ++c) out[bb * 8 + c] = logits[c] - lse;
    }
}

// ---------------------------------------------------------------------------
extern "C" void kernel_launch(void* const* d_in, const int* in_sizes, int n_in,
                              void* d_out, int out_size, void* d_ws, size_t ws_size,
                              hipStream_t stream)
{
    const float* x    = (const float*)d_in[0];
    const float* Wemb = (const float*)d_in[1];
    const float* bemb = (const float*)d_in[2];
    const float* Wqkv = (const float*)d_in[3];
    const float* bqkv = (const float*)d_in[4];
    const float* Wo   = (const float*)d_in[5];
    const float* bo   = (const float*)d_in[6];
    const float* W1   = (const float*)d_in[7];
    const float* b1f  = (const float*)d_in[8];
    const float* W2   = (const float*)d_in[9];
    const float* b2f  = (const float*)d_in[10];
    const float* g1   = (const float*)d_in[11];
    const float* be1  = (const float*)d_in[12];
    const float* g2   = (const float*)d_in[13];
    const float* be2  = (const float*)d_in[14];
    const float* Wcls = (const float*)d_in[15];
    const float* bcls = (const float*)d_in[16];
    float* out = (float*)d_out;

    // -------- workspace layout --------
    float*  h    = (float*)d_ws;                       // 8000x512 f32
    float*  tmpF = h + (size_t)MROWS * DMODEL;         // 8000x512 f32
    __bf16* hb   = (__bf16*)(tmpF + (size_t)MROWS * DMODEL);   // 8000x512
    __bf16* qkvb = hb + (size_t)MROWS * DMODEL;        // 8000x1536
    __bf16* attb = qkvb + (size_t)MROWS * 3 * DMODEL;  // 8000x512
    __bf16* ff1b = qkvb;                               // alias: 8000x2048
    __bf16* xb   = attb + (size_t)MROWS * DMODEL;      // 8000x256
    __bf16* wb   = xb + (size_t)MROWS * 256;
    __bf16* wEmb = wb;
    __bf16* wQKV = wEmb + 512 * 256;
    __bf16* wWo  = wQKV + (size_t)NLAYER * 3 * DMODEL * DMODEL;
    __bf16* wW1  = wWo  + (size_t)NLAYER * DMODEL * DMODEL;
    __bf16* wW2  = wW1  + (size_t)NLAYER * FFDIM * DMODEL;

    dim3 blk(256);

    f2bf<<<dim3(MROWS * 256 / 1024), blk, 0, stream>>>(x, xb);
    f2bf<<<dim3(512 * 256 / 1024), blk, 0, stream>>>(Wemb, wEmb);
    f2bf<<<dim3(NLAYER * 3 * DMODEL * DMODEL / 1024), blk, 0, stream>>>(Wqkv, wQKV);
    f2bf<<<dim3(NLAYER * DMODEL * DMODEL / 1024), blk, 0, stream>>>(Wo, wWo);
    f2bf<<<dim3(NLAYER * FFDIM * DMODEL / 1024), blk, 0, stream>>>(W1, wW1);
    f2bf<<<dim3(NLAYER * DMODEL * FFDIM / 1024), blk, 0, stream>>>(W2, wW2);

    gemm_bf16<true, false, false><<<dim3(4, 63), blk, 0, stream>>>(
        xb, wEmb, bemb, h, nullptr, MROWS, DMODEL, 256);
    add_pe<<<dim3(MROWS * DMODEL / 256), blk, 0, stream>>>(h, hb);

    for (int l = 0; l < NLAYER; ++l) {
        gemm_bf16<false, true, false><<<dim3(12, 63), blk, 0, stream>>>(
            hb, wQKV + (size_t)l * 3 * DMODEL * DMODEL, bqkv + (size_t)l * 3 * DMODEL,
            nullptr, qkvb, MROWS, 3 * DMODEL, DMODEL);
        // 2048 waves: 8b x 8h x 32 q-tiles, 4 waves per 256-thread block
        attn_mfma<<<dim3(512), blk, 0, stream>>>(qkvb, attb);
        gemm_bf16<true, false, false><<<dim3(4, 63), blk, 0, stream>>>(
            attb, wWo + (size_t)l * DMODEL * DMODEL, bo + (size_t)l * DMODEL,
            tmpF, nullptr, MROWS, DMODEL, DMODEL);
        add_ln<<<dim3(MROWS / 4), blk, 0, stream>>>(
            h, tmpF, g1 + (size_t)l * DMODEL, be1 + (size_t)l * DMODEL, hb);
        gemm_bf16<false, true, true><<<dim3(16, 63), blk, 0, stream>>>(
            hb, wW1 + (size_t)l * FFDIM * DMODEL, b1f + (size_t)l * FFDIM,
            nullptr, ff1b, MROWS, FFDIM, DMODEL);
        gemm_bf16<true, false, false><<<dim3(4, 63), blk, 0, stream>>>(
            ff1b, wW2 + (size_t)l * DMODEL * FFDIM, b2f + (size_t)l * DMODEL,
            tmpF, nullptr, MROWS, DMODEL, FFDIM);
        add_ln<<<dim3(MROWS / 4), blk, 0, stream>>>(
            h, tmpF, g2 + (size_t)l * DMODEL, be2 + (size_t)l * DMODEL, hb);
    }

    pool_cls<<<dim3(8), blk, 0, stream>>>(h, Wcls, bcls, out);
}

// Round 4
// 910.180 us; speedup vs baseline: 8.1357x; 1.3297x over previous
//
#include <hip/hip_runtime.h>
#include <math.h>

#define T_SEQ   1000
#define BATCH   8
#define DMODEL  512
#define NHEAD   8
#define DHEAD   64
#define FFDIM   2048
#define NLAYER  4
#define MROWS   (BATCH * T_SEQ)   // 8000
#define TCHUNK  25                // pooling pass-1 chunks (40 t each)

typedef __bf16 bf16x8 __attribute__((ext_vector_type(8)));
typedef __bf16 bf16x4 __attribute__((ext_vector_type(4)));
typedef float  f32x4  __attribute__((ext_vector_type(4)));
typedef float  f32x16 __attribute__((ext_vector_type(16)));

#define GL2LDS(g, l) \
    __builtin_amdgcn_global_load_lds((const __attribute__((address_space(1))) void*)(g), \
                                     (__attribute__((address_space(3))) void*)(l), 16, 0, 0)

// ---------------------------------------------------------------------------
// fp32 -> bf16 convert, 4 elems/thread.
// ---------------------------------------------------------------------------
__global__ __launch_bounds__(256)
void f2bf(const float* __restrict__ in, __bf16* __restrict__ out)
{
    int i = (blockIdx.x * 256 + threadIdx.x) * 4;
    float4 v = *(const float4*)(in + i);
    bf16x4 o;
    o[0] = (__bf16)v.x; o[1] = (__bf16)v.y; o[2] = (__bf16)v.z; o[3] = (__bf16)v.w;
    *(bf16x4*)(out + i) = o;
}

// ---------------------------------------------------------------------------
// bf16 MFMA GEMM (m97 structure): C(MxN) = A(MxK) @ B(NxK)^T + bias.
// ---------------------------------------------------------------------------
template<bool WF32, bool WBF16, bool RELU>
__global__ __launch_bounds__(256)
void gemm_bf16(const __bf16* __restrict__ A, const __bf16* __restrict__ B,
               const float* __restrict__ bias, float* __restrict__ Cf,
               __bf16* __restrict__ Cb, int M, int N, int K)
{
    __shared__ __align__(16) __bf16 As[128 * 64];
    __shared__ __align__(16) __bf16 Bs[128 * 64];

    const int tid  = threadIdx.x;
    const int lane = tid & 63;
    const int w    = tid >> 6;
    const int wr   = w >> 1, wc = w & 1;
    const int row0 = blockIdx.y * 128;
    const int col0 = blockIdx.x * 128;

    size_t aoffg[4], boffg[4];
    int    ldso[4];
    #pragma unroll
    for (int p = 0; p < 4; ++p) {
        int bo = p * 4096 + tid * 16;
        int r  = bo >> 7;
        int cb = bo & 127;
        int ga = row0 + r; if (ga > M - 1) ga = M - 1;
        aoffg[p] = (size_t)ga * K * 2 + cb;
        boffg[p] = (size_t)(col0 + r) * K * 2 + cb;
        ldso[p]  = bo;
    }

    f32x4 acc[4][4];
    #pragma unroll
    for (int m = 0; m < 4; ++m)
        #pragma unroll
        for (int n = 0; n < 4; ++n) acc[m][n] = (f32x4)0.f;

    const char* gA = (const char*)A;
    const char* gB = (const char*)B;
    char*       lA = (char*)As;
    char*       lB = (char*)Bs;

    for (int kt = 0; kt < K; kt += 64) {
        const size_t kb = (size_t)kt * 2;
        #pragma unroll
        for (int p = 0; p < 4; ++p) {
            GL2LDS(gA + aoffg[p] + kb, lA + ldso[p]);
            GL2LDS(gB + boffg[p] + kb, lB + ldso[p]);
        }
        __syncthreads();
        #pragma unroll
        for (int ks = 0; ks < 2; ++ks) {
            bf16x8 af[4], bfr[4];
            #pragma unroll
            for (int m = 0; m < 4; ++m) {
                int rr = wr * 64 + m * 16 + (lane & 15);
                af[m] = *(const bf16x8*)(As + rr * 64 + ks * 32 + (lane >> 4) * 8);
            }
            #pragma unroll
            for (int n = 0; n < 4; ++n) {
                int rr = wc * 64 + n * 16 + (lane & 15);
                bfr[n] = *(const bf16x8*)(Bs + rr * 64 + ks * 32 + (lane >> 4) * 8);
            }
            #pragma unroll
            for (int m = 0; m < 4; ++m)
                #pragma unroll
                for (int n = 0; n < 4; ++n)
                    acc[m][n] = __builtin_amdgcn_mfma_f32_16x16x32_bf16(af[m], bfr[n], acc[m][n], 0, 0, 0);
        }
        __syncthreads();
    }

    const int crow = (lane >> 4) * 4;
    const int ccol = lane & 15;
    #pragma unroll
    for (int n = 0; n < 4; ++n) {
        const int gc = col0 + wc * 64 + n * 16 + ccol;
        const float bv = bias[gc];
        #pragma unroll
        for (int m = 0; m < 4; ++m) {
            const int gr0 = row0 + wr * 64 + m * 16 + crow;
            #pragma unroll
            for (int r = 0; r < 4; ++r) {
                const int gr = gr0 + r;
                if (gr >= M) continue;
                float v = acc[m][n][r] + bv;
                if (RELU) v = fmaxf(v, 0.f);
                if (WF32)  Cf[(size_t)gr * N + gc] = v;
                if (WBF16) Cb[(size_t)gr * N + gc] = (__bf16)v;
            }
        }
    }
}

// ---------------------------------------------------------------------------
// Add sinusoidal PE in place (fp32) + write bf16 shadow.
// ---------------------------------------------------------------------------
__global__ __launch_bounds__(256)
void add_pe(float* __restrict__ hbuf, __bf16* __restrict__ hb)
{
    int idx = blockIdx.x * 256 + threadIdx.x;
    int d   = idx & (DMODEL - 1);
    int t   = (idx >> 9) % T_SEQ;
    float freq = expf((float)(d & ~1) * (-9.210340371976184f / (float)DMODEL));
    float ang  = (float)t * freq;
    float pe   = (d & 1) ? cosf(ang) : sinf(ang);
    float v = hbuf[idx] + pe;
    hbuf[idx] = v;
    hb[idx]   = (__bf16)v;
}

// ---------------------------------------------------------------------------
// MFMA flash attention over the band, 32x32x16, swapped-operand structure.
// ---------------------------------------------------------------------------
__global__ __launch_bounds__(256)
void attn_mfma(const __bf16* __restrict__ qkv, __bf16* __restrict__ o)
{
    const int wv   = (blockIdx.x << 2) + (threadIdx.x >> 6);
    const int lane = threadIdx.x & 63;
    const int qt   = wv & 31;
    const int hh   = (wv >> 5) & 7;
    const int b    = wv >> 8;
    const int qb   = qt * 32;
    const int half = lane >> 5;
    const int ql   = lane & 31;
    const int i    = qb + ql;
    const int iq   = (i < T_SEQ) ? i : (T_SEQ - 1);

    const int RS = 3 * DMODEL;
    const __bf16* Q = qkv + (size_t)b * T_SEQ * RS + hh * DHEAD;
    const __bf16* K = Q + DMODEL;
    const __bf16* V = Q + 2 * DMODEL;

    bf16x8 qf[4];
    {
        const __bf16* qrow = Q + (size_t)iq * RS + half * 8;
        #pragma unroll
        for (int ds = 0; ds < 4; ++ds)
            qf[ds] = *(const bf16x8*)(qrow + ds * 16);
    }

    const int w = 25 * (hh + 1);
    const int kb_lo = (qb - w > 0 ? qb - w : 0) & ~31;
    const int kb_hi = (qb + 31 + w < T_SEQ - 1) ? (qb + 31 + w) : (T_SEQ - 1);
    const int  spanv = (2 * w < T_SEQ - 1 - i + w) ? 2 * w : (T_SEQ - 1 - i + w);
    const unsigned span = (unsigned)spanv;
    const float C2 = 0.125f * 1.44269504089f;

    float m2 = -1e9f, l = 0.f;
    f32x16 oa0 = (f32x16)0.f, oa1 = (f32x16)0.f;

    for (int kb = kb_lo; kb <= kb_hi; kb += 32) {
        f32x16 sv = (f32x16)0.f;
        {
            int krow = kb + ql; if (krow > T_SEQ - 1) krow = T_SEQ - 1;
            const __bf16* kr = K + (size_t)krow * RS + half * 8;
            #pragma unroll
            for (int ds = 0; ds < 4; ++ds) {
                bf16x8 kf = *(const bf16x8*)(kr + ds * 16);
                sv = __builtin_amdgcn_mfma_f32_32x32x16_bf16(kf, qf[ds], sv, 0, 0, 0);
            }
        }

        const int base = kb - i + w;
        float s2[16];
        #pragma unroll
        for (int r = 0; r < 16; ++r) {
            const int kr = (r & 3) + 8 * (r >> 2) + 4 * half;
            const unsigned jrel = (unsigned)(base + kr);
            s2[r] = (jrel <= span) ? sv[r] * C2 : -1e9f;
        }

        float mx = s2[0];
        #pragma unroll
        for (int r = 1; r < 16; ++r) mx = fmaxf(mx, s2[r]);
        mx = fmaxf(mx, __shfl_xor(mx, 32, 64));

        if (!__all(mx <= m2 + 8.0f)) {
            const float mnew  = fmaxf(m2, mx);
            const float scale = exp2f(m2 - mnew);
            m2 = mnew;
            l *= scale;
            #pragma unroll
            for (int r = 0; r < 16; ++r) {
                const int qsrc = (r & 3) + 8 * (r >> 2) + 4 * half;
                const float sc = __shfl(scale, qsrc, 64);
                oa0[r] *= sc;
                oa1[r] *= sc;
            }
        }

        float p[16];
        float ps = 0.f;
        #pragma unroll
        for (int r = 0; r < 16; ++r) { p[r] = exp2f(s2[r] - m2); ps += p[r]; }
        ps += __shfl_xor(ps, 32, 64);
        l += ps;

        unsigned pk[8];
        #pragma unroll
        for (int t = 0; t < 8; ++t) {
            union { unsigned u; __bf16 h[2]; } cv;
            cv.h[0] = (__bf16)p[2 * t];
            cv.h[1] = (__bf16)p[2 * t + 1];
            pk[t] = cv.u;
        }
        unsigned y[8];
        #pragma unroll
        for (int t = 0; t < 8; ++t)
            y[t] = (unsigned)__shfl_xor((int)pk[t], 32, 64);

        union { unsigned u[4]; bf16x8 v; } pa0, pa1;
        if (half == 0) {
            pa0.u[0] = pk[0]; pa0.u[1] = pk[1]; pa0.u[2] = y[0];  pa0.u[3] = y[1];
            pa1.u[0] = pk[4]; pa1.u[1] = pk[5]; pa1.u[2] = y[4];  pa1.u[3] = y[5];
        } else {
            pa0.u[0] = y[2];  pa0.u[1] = y[3];  pa0.u[2] = pk[2]; pa0.u[3] = pk[3];
            pa1.u[0] = y[6];  pa1.u[1] = y[7];  pa1.u[2] = pk[6]; pa1.u[3] = pk[7];
        }

        #pragma unroll
        for (int ks = 0; ks < 2; ++ks) {
            const int R0 = kb + ks * 16 + half * 8;
            #pragma unroll
            for (int dh = 0; dh < 2; ++dh) {
                bf16x8 vf;
                const __bf16* vcol = V + dh * 32 + ql;
                #pragma unroll
                for (int j = 0; j < 8; ++j) {
                    int rr = R0 + j; if (rr > T_SEQ - 1) rr = T_SEQ - 1;
                    vf[j] = vcol[(size_t)rr * RS];
                }
                if (dh == 0)
                    oa0 = __builtin_amdgcn_mfma_f32_32x32x16_bf16(ks ? pa1.v : pa0.v, vf, oa0, 0, 0, 0);
                else
                    oa1 = __builtin_amdgcn_mfma_f32_32x32x16_bf16(ks ? pa1.v : pa0.v, vf, oa1, 0, 0, 0);
            }
        }
    }

    const float rinv = 1.f / l;
    __bf16* ob = o + ((size_t)b * T_SEQ) * DMODEL + hh * DHEAD;
    #pragma unroll
    for (int r = 0; r < 16; ++r) {
        const int q   = (r & 3) + 8 * (r >> 2) + 4 * half;
        const int row = qb + q;
        const float ri = __shfl(rinv, q, 64);
        if (row < T_SEQ) {
            ob[(size_t)row * DMODEL + ql]      = (__bf16)(oa0[r] * ri);
            ob[(size_t)row * DMODEL + 32 + ql] = (__bf16)(oa1[r] * ri);
        }
    }
}

// ---------------------------------------------------------------------------
// h = LayerNorm(h + t) * g + b (fp32 residual stream) + bf16 shadow.
// ---------------------------------------------------------------------------
__global__ __launch_bounds__(256)
void add_ln(float* __restrict__ hbuf, const float* __restrict__ tbuf,
            const float* __restrict__ g, const float* __restrict__ b,
            __bf16* __restrict__ hb)
{
    const int row  = blockIdx.x * 4 + (threadIdx.x >> 6);
    const int lane = threadIdx.x & 63;
    float*       hp = hbuf + (size_t)row * DMODEL + lane * 8;
    const float* tp = tbuf + (size_t)row * DMODEL + lane * 8;

    float xv[8];
    float4 h0 = *(const float4*)hp;   float4 h1 = *(const float4*)(hp + 4);
    float4 t0 = *(const float4*)tp;   float4 t1 = *(const float4*)(tp + 4);
    xv[0] = h0.x + t0.x; xv[1] = h0.y + t0.y; xv[2] = h0.z + t0.z; xv[3] = h0.w + t0.w;
    xv[4] = h1.x + t1.x; xv[5] = h1.y + t1.y; xv[6] = h1.z + t1.z; xv[7] = h1.w + t1.w;

    float s = 0.f;
    #pragma unroll
    for (int j = 0; j < 8; ++j) s += xv[j];
    #pragma unroll
    for (int off = 32; off >= 1; off >>= 1) s += __shfl_xor(s, off, 64);
    float mean = s * (1.f / DMODEL);

    float vs = 0.f;
    #pragma unroll
    for (int j = 0; j < 8; ++j) { float d = xv[j] - mean; vs += d * d; }
    #pragma unroll
    for (int off = 32; off >= 1; off >>= 1) vs += __shfl_xor(vs, off, 64);
    float rstd = rsqrtf(vs * (1.f / DMODEL) + 1e-5f);

    float4 g0 = *(const float4*)(g + lane * 8);
    float4 g1 = *(const float4*)(g + lane * 8 + 4);
    float4 b0 = *(const float4*)(b + lane * 8);
    float4 b1 = *(const float4*)(b + lane * 8 + 4);
    float gg[8] = {g0.x, g0.y, g0.z, g0.w, g1.x, g1.y, g1.z, g1.w};
    float bb[8] = {b0.x, b0.y, b0.z, b0.w, b1.x, b1.y, b1.z, b1.w};

    float outv[8];
    bf16x8 ob;
    #pragma unroll
    for (int j = 0; j < 8; ++j) {
        outv[j] = (xv[j] - mean) * rstd * gg[j] + bb[j];
        ob[j] = (__bf16)outv[j];
    }
    *(float4*)hp       = *(float4*)&outv[0];
    *(float4*)(hp + 4) = *(float4*)&outv[4];
    *(bf16x8*)(hb + (size_t)row * DMODEL + lane * 8) = ob;
}

// ---------------------------------------------------------------------------
// Max-pool pass 1: grid (BATCH, TCHUNK). Each block max-reduces 40 time rows
// over all 512 d into part[b][chunk][d].
// ---------------------------------------------------------------------------
__global__ __launch_bounds__(256)
void pool_p1(const float* __restrict__ hbuf, float* __restrict__ part)
{
    const int bb  = blockIdx.x;
    const int tc  = blockIdx.y;
    const int tid = threadIdx.x;
    const int t0  = tc * (T_SEQ / TCHUNK);
    const float* p = hbuf + ((size_t)bb * T_SEQ + t0) * DMODEL;

    float mx0 = -3.4e38f, mx1 = -3.4e38f;
    for (int t = 0; t < T_SEQ / TCHUNK; ++t) {
        mx0 = fmaxf(mx0, p[(size_t)t * DMODEL + tid]);
        mx1 = fmaxf(mx1, p[(size_t)t * DMODEL + 256 + tid]);
    }
    float* q = part + ((size_t)bb * TCHUNK + tc) * DMODEL;
    q[tid]       = mx0;
    q[tid + 256] = mx1;
}

// ---------------------------------------------------------------------------
// Max-pool pass 2 + classifier + log_softmax. One block per batch item.
// ---------------------------------------------------------------------------
__global__ __launch_bounds__(256)
void pool_p2(const float* __restrict__ part, const float* __restrict__ Wcls,
             const float* __restrict__ bcls, float* __restrict__ out)
{
    __shared__ float pooled[DMODEL];
    __shared__ float logits[8];
    const int bb  = blockIdx.x;
    const int tid = threadIdx.x;

    const float* q = part + (size_t)bb * TCHUNK * DMODEL;
    #pragma unroll
    for (int u = 0; u < 2; ++u) {
        const int d = tid + u * 256;
        float mx = -3.4e38f;
        for (int c = 0; c < TCHUNK; ++c) mx = fmaxf(mx, q[(size_t)c * DMODEL + d]);
        pooled[d] = mx;
    }
    __syncthreads();

    // 8 classes x 32 lanes each: lane-strided dot over 512 dims
    const int cls  = tid >> 5;          // 0..7
    const int lsub = tid & 31;          // 0..31
    const float* wr = Wcls + cls * DMODEL;
    float s = 0.f;
    #pragma unroll
    for (int u = 0; u < 16; ++u) {
        const int d = lsub + u * 32;
        s = fmaf(pooled[d], wr[d], s);
    }
    #pragma unroll
    for (int off = 16; off >= 1; off >>= 1) s += __shfl_xor(s, off, 32);
    if (lsub == 0) logits[cls] = s + bcls[cls];
    __syncthreads();

    if (tid == 0) {
        float mx = logits[0];
        for (int c = 1; c < 8; ++c) mx = fmaxf(mx, logits[c]);
        float se = 0.f;
        for (int c = 0; c < 8; ++c) se += expf(logits[c] - mx);
        float lse = logf(se) + mx;
        for (int c = 0; c < 8; ++c) out[bb * 8 + c] = logits[c] - lse;
    }
}

// ---------------------------------------------------------------------------
extern "C" void kernel_launch(void* const* d_in, const int* in_sizes, int n_in,
                              void* d_out, int out_size, void* d_ws, size_t ws_size,
                              hipStream_t stream)
{
    const float* x    = (const float*)d_in[0];
    const float* Wemb = (const float*)d_in[1];
    const float* bemb = (const float*)d_in[2];
    const float* Wqkv = (const float*)d_in[3];
    const float* bqkv = (const float*)d_in[4];
    const float* Wo   = (const float*)d_in[5];
    const float* bo   = (const float*)d_in[6];
    const float* W1   = (const float*)d_in[7];
    const float* b1f  = (const float*)d_in[8];
    const float* W2   = (const float*)d_in[9];
    const float* b2f  = (const float*)d_in[10];
    const float* g1   = (const float*)d_in[11];
    const float* be1  = (const float*)d_in[12];
    const float* g2   = (const float*)d_in[13];
    const float* be2  = (const float*)d_in[14];
    const float* Wcls = (const float*)d_in[15];
    const float* bcls = (const float*)d_in[16];
    float* out = (float*)d_out;

    // -------- workspace layout --------
    float*  h    = (float*)d_ws;                       // 8000x512 f32
    float*  tmpF = h + (size_t)MROWS * DMODEL;         // 8000x512 f32 (also pool partials)
    __bf16* hb   = (__bf16*)(tmpF + (size_t)MROWS * DMODEL);   // 8000x512
    __bf16* qkvb = hb + (size_t)MROWS * DMODEL;        // 8000x1536
    __bf16* attb = qkvb + (size_t)MROWS * 3 * DMODEL;  // 8000x512
    __bf16* ff1b = qkvb;                               // alias: 8000x2048
    __bf16* xb   = attb + (size_t)MROWS * DMODEL;      // 8000x256
    __bf16* wb   = xb + (size_t)MROWS * 256;
    __bf16* wEmb = wb;
    __bf16* wQKV = wEmb + 512 * 256;
    __bf16* wWo  = wQKV + (size_t)NLAYER * 3 * DMODEL * DMODEL;
    __bf16* wW1  = wWo  + (size_t)NLAYER * DMODEL * DMODEL;
    __bf16* wW2  = wW1  + (size_t)NLAYER * FFDIM * DMODEL;

    dim3 blk(256);

    f2bf<<<dim3(MROWS * 256 / 1024), blk, 0, stream>>>(x, xb);
    f2bf<<<dim3(512 * 256 / 1024), blk, 0, stream>>>(Wemb, wEmb);
    f2bf<<<dim3(NLAYER * 3 * DMODEL * DMODEL / 1024), blk, 0, stream>>>(Wqkv, wQKV);
    f2bf<<<dim3(NLAYER * DMODEL * DMODEL / 1024), blk, 0, stream>>>(Wo, wWo);
    f2bf<<<dim3(NLAYER * FFDIM * DMODEL / 1024), blk, 0, stream>>>(W1, wW1);
    f2bf<<<dim3(NLAYER * DMODEL * FFDIM / 1024), blk, 0, stream>>>(W2, wW2);

    gemm_bf16<true, false, false><<<dim3(4, 63), blk, 0, stream>>>(
        xb, wEmb, bemb, h, nullptr, MROWS, DMODEL, 256);
    add_pe<<<dim3(MROWS * DMODEL / 256), blk, 0, stream>>>(h, hb);

    for (int l = 0; l < NLAYER; ++l) {
        gemm_bf16<false, true, false><<<dim3(12, 63), blk, 0, stream>>>(
            hb, wQKV + (size_t)l * 3 * DMODEL * DMODEL, bqkv + (size_t)l * 3 * DMODEL,
            nullptr, qkvb, MROWS, 3 * DMODEL, DMODEL);
        attn_mfma<<<dim3(512), blk, 0, stream>>>(qkvb, attb);
        gemm_bf16<true, false, false><<<dim3(4, 63), blk, 0, stream>>>(
            attb, wWo + (size_t)l * DMODEL * DMODEL, bo + (size_t)l * DMODEL,
            tmpF, nullptr, MROWS, DMODEL, DMODEL);
        add_ln<<<dim3(MROWS / 4), blk, 0, stream>>>(
            h, tmpF, g1 + (size_t)l * DMODEL, be1 + (size_t)l * DMODEL, hb);
        gemm_bf16<false, true, true><<<dim3(16, 63), blk, 0, stream>>>(
            hb, wW1 + (size_t)l * FFDIM * DMODEL, b1f + (size_t)l * FFDIM,
            nullptr, ff1b, MROWS, FFDIM, DMODEL);
        gemm_bf16<true, false, false><<<dim3(4, 63), blk, 0, stream>>>(
            ff1b, wW2 + (size_t)l * DMODEL * FFDIM, b2f + (size_t)l * DMODEL,
            tmpF, nullptr, MROWS, DMODEL, FFDIM);
        add_ln<<<dim3(MROWS / 4), blk, 0, stream>>>(
            h, tmpF, g2 + (size_t)l * DMODEL, be2 + (size_t)l * DMODEL, hb);
    }

    // parallel max-pool (partials overwrite tmpF, which is dead here) + classifier
    pool_p1<<<dim3(BATCH, TCHUNK), blk, 0, stream>>>(h, tmpF);
    pool_p2<<<dim3(BATCH), blk, 0, stream>>>(tmpF, Wcls, bcls, out);
}